// Round 21
// baseline (144.648 us; speedup 1.0000x reference)
//
#include <hip/hip_runtime.h>
#include <math.h>

#define NM 50000
#define ND 50000
#define NN 100000   // total nodes
#define DK 256      // feature dim of both sims
#define F  64       // attn feature size
#define SLOPE 0.2f

#define NBZ   391   // ceil(50000/128) proj blocks per half (128 rows/block)
#define NPROJ (NBZ * 2)

// edge binning: 64-node buckets (R20 lesson: quarter-filtering cost 8x redundant
// bucket streaming; bin at final granularity instead)
#define NB64  1563  // ceil(100000/64)
#define QBCAP 2048  // per-bucket capacity (mean 1024, +32sigma)
#define CH    4096  // edges per bin block
#define NPAD  2048  // padded counter array (4 per thread x 512)

typedef short bf16x8 __attribute__((ext_vector_type(8)));
typedef float f32x4  __attribute__((ext_vector_type(4)));

// fp32 -> (hi, lo) bf16 split, rne both halves
__device__ __forceinline__ void cvt8(const float4& a0, const float4& a1,
                                     bf16x8& hi, bf16x8& lo) {
    float v[8] = {a0.x, a0.y, a0.z, a0.w, a1.x, a1.y, a1.z, a1.w};
    #pragma unroll
    for (int e = 0; e < 8; ++e) {
        unsigned u  = __float_as_uint(v[e]);
        unsigned r  = u + 0x7FFF + ((u >> 16) & 1);
        unsigned short hb = (unsigned short)(r >> 16);
        float hf = __uint_as_float(((unsigned)hb) << 16);
        float lf = v[e] - hf;
        unsigned ul = __float_as_uint(lf);
        unsigned rl = ul + 0x7FFF + ((ul >> 16) & 1);
        hi[e] = (short)hb;
        lo[e] = (short)(rl >> 16);
    }
}

// ================= fused kernel 1: bin (blocks 0..nchunks-1) ∥ proj (rest) =================
__global__ __launch_bounds__(512, 1) void fused1(const float* __restrict__ m_sim,
                                                 const float* __restrict__ d_sim,
                                                 const float* __restrict__ Wm,
                                                 const float* __restrict__ Wd,
                                                 float* __restrict__ z,
                                                 const int* __restrict__ src,
                                                 const int* __restrict__ dst,
                                                 int* __restrict__ pkb_g,
                                                 int* __restrict__ bcur,
                                                 int nchunks, int E) {
    __shared__ __align__(16) char smem[65536];   // 64 KB union
    int t = threadIdx.x;

    if ((int)blockIdx.x < nchunks) {
        // ---------------- bin path (512 threads, 58 KB) ----------------
        // 64-node buckets: cnt/lcur/gbase [2048] + sp [512] + pkb_l/bkt_l [4096]
        int* cnt   = (int*)smem;          // 2048 (8 KB)
        int* lcur  = cnt + NPAD;          // 2048 (8 KB)
        int* gbase = lcur + NPAD;         // 2048 (8 KB)
        int* sp    = gbase + NPAD;        // 512  (2 KB)
        int* pkb_l = sp + 512;            // 4096 (16 KB)
        int* bkt_l = pkb_l + CH;          // 4096 (16 KB)

        int base = blockIdx.x * CH;
        int chunkN = E - base; if (chunkN > CH) chunkN = CH;

        #pragma unroll
        for (int e = 0; e < 4; ++e) cnt[e * 512 + t] = 0;
        __syncthreads();

        int ss[8], ds[8];
        #pragma unroll
        for (int e = 0; e < 8; ++e) {
            int k = base + e * 512 + t;
            if (e * 512 + t < chunkN) {
                ds[e] = dst[k];
                ss[e] = src[k];
                atomicAdd(&cnt[ds[e] >> 6], 1);
            }
        }
        __syncthreads();

        // scan 2048 counters: 4 consecutive per thread (scanA pattern)
        int c4[4], run = 0;
        #pragma unroll
        for (int e = 0; e < 4; ++e) { c4[e] = cnt[t * 4 + e]; run += c4[e]; }
        sp[t] = run;
        __syncthreads();
        for (int off = 1; off < 512; off <<= 1) {
            int v = (t >= off) ? sp[t - off] : 0;
            __syncthreads();
            sp[t] += v;
            __syncthreads();
        }
        int texcl = sp[t] - run;
        #pragma unroll
        for (int e = 0; e < 4; ++e) {
            int b = t * 4 + e;
            lcur[b] = texcl;           // exclusive local offset
            gbase[b] = (c4[e] > 0) ? atomicAdd(&bcur[b], c4[e]) : 0;
            texcl += c4[e];
        }
        __syncthreads();

        #pragma unroll
        for (int e = 0; e < 8; ++e) {
            if (e * 512 + t < chunkN) {
                int b = ds[e] >> 6;
                int p = atomicAdd(&lcur[b], 1);
                pkb_l[p] = (ss[e] << 6) | (ds[e] & 63);
                bkt_l[p] = b;
            }
        }
        __syncthreads();
        // post-scatter: lcur[b] = inclusive; exclusive = lcur[b] - cnt[b]

        for (int idx = t; idx < chunkN; idx += 512) {
            int b = bkt_l[idx];
            int g = b * QBCAP + gbase[b] + (idx - (lcur[b] - cnt[b]));
            pkb_g[g] = pkb_l[idx];
        }
        return;
    }

    // ---------------- proj path (512 threads, 64 KB) ----------------
    short* Whi = (short*)smem;            // 64 x 256 bf16 = 32 KB, ps = ls^(row&7)
    short* Wlo = (short*)(smem + 32768);  // 32 KB

    int bid  = blockIdx.x - nchunks;
    bool ism = bid < NBZ;
    const float* sim = ism ? m_sim : d_sim;
    const float* W   = ism ? Wm : Wd;
    int row0   = (ism ? bid : bid - NBZ) * 128;
    int nrows  = ism ? NM : ND;
    int zbase  = ism ? 0 : NM;

    int l = t & 63;           // lane
    int w = t >> 6;           // wave 0..7
    int frow = l & 15;        // A row within wave stripe / B col within tile
    int kg   = l >> 4;        // k-group 0..3

    int grow = row0 + w * 16 + frow; if (grow > nrows - 1) grow = nrows - 1;
    const float4* ap = (const float4*)(sim + (size_t)grow * DK) + kg * 2;

    // prefetch steps 0 and 1 (land during W conversion)
    float4 pa0 = ap[0], pa1 = ap[1];
    float4 pb0 = ap[8], pb1 = ap[9];

    // ---- W -> LDS bf16 hi+lo, once per block (write-side XOR ps = ls^(r&7)) ----
    {
        int r = t >> 3;                   // row 0..63
        int q = t & 7;                    // slot quarter 0..7
        const float4* wr = (const float4*)(W + (size_t)r * DK);
        #pragma unroll
        for (int i = 0; i < 4; ++i) {
            int ls = q * 4 + i;           // logical slot 0..31
            float4 b0 = wr[ls * 2], b1 = wr[ls * 2 + 1];
            bf16x8 hi, lo;
            cvt8(b0, b1, hi, lo);
            int ps = ls ^ (r & 7);
            *(bf16x8*)&Whi[r * 256 + ps * 8] = hi;
            *(bf16x8*)&Wlo[r * 256 + ps * 8] = lo;
        }
    }
    __syncthreads();   // W tiles ready; no further barriers needed

    f32x4 acc[4];
    #pragma unroll
    for (int j = 0; j < 4; ++j) acc[j] = (f32x4){0.f, 0.f, 0.f, 0.f};

    #pragma unroll 1
    for (int step = 0; step < 8; ++step) {
        bf16x8 ahi, alo;
        cvt8(pa0, pa1, ahi, alo);
        pa0 = pb0; pa1 = pb1;
        if (step + 2 < 8) {
            pb0 = ap[(step + 2) * 8];
            pb1 = ap[(step + 2) * 8 + 1];
        }

        int ls = step * 4 + kg;
        #pragma unroll
        for (int j = 0; j < 4; ++j) {
            int wrow = j * 16 + frow;
            int ps = ls ^ (wrow & 7);
            bf16x8 bhi = *(const bf16x8*)&Whi[wrow * 256 + ps * 8];
            bf16x8 blo = *(const bf16x8*)&Wlo[wrow * 256 + ps * 8];
            acc[j] = __builtin_amdgcn_mfma_f32_16x16x32_bf16(ahi, bhi, acc[j], 0, 0, 0);
            acc[j] = __builtin_amdgcn_mfma_f32_16x16x32_bf16(ahi, blo, acc[j], 0, 0, 0);
            acc[j] = __builtin_amdgcn_mfma_f32_16x16x32_bf16(alo, bhi, acc[j], 0, 0, 0);
        }
    }

    // D layout (verified m89): col = lane&15, row = (lane>>4)*4 + reg
    #pragma unroll
    for (int j = 0; j < 4; ++j) {
        #pragma unroll
        for (int reg = 0; reg < 4; ++reg) {
            int r = row0 + w * 16 + kg * 4 + reg;
            if (r < nrows)
                z[((zbase + r) << 6) + j * 16 + frow] = acc[j][reg];
        }
    }
}

// ================= gat2 v2: block = 64-node bucket, no filtering =================
// Phase 1: read exactly own ~1024 edges (2 passes), hist(64)+scan+LDS scatter.
// Phase 2: 4 waves x 16 nodes, aggregation identical to the verified gat.
__global__ __launch_bounds__(256) void gat2(const float* __restrict__ z,
                                            const int* __restrict__ pkb_g,
                                            const int* __restrict__ bcur,
                                            float* __restrict__ out) {
    __shared__ int dcnt[64], loc[64], lcur[64];
    __shared__ int csr_l[QBCAP];

    int t  = threadIdx.x;
    int b  = blockIdx.x;          // bucket = 64 nodes
    int node0 = b << 6;
    int nbe = bcur[b];
    const int* pp = pkb_g + (size_t)b * QBCAP;

    if (t < 64) dcnt[t] = 0;
    __syncthreads();
    for (int i = t; i < nbe; i += 256)
        atomicAdd(&dcnt[pp[i] & 63], 1);
    __syncthreads();
    if (t < 64) loc[t] = dcnt[t];
    __syncthreads();
    for (int off = 1; off < 64; off <<= 1) {
        int v = (t < 64 && t >= off) ? loc[t - off] : 0;
        __syncthreads();
        if (t < 64) loc[t] += v;
        __syncthreads();
    }
    if (t < 64) { int e0 = loc[t] - dcnt[t]; loc[t] = e0; lcur[t] = e0; }
    __syncthreads();
    for (int i = t; i < nbe; i += 256) {
        int pk = pp[i];
        int pos = atomicAdd(&lcur[pk & 63], 1);
        csr_l[pos] = pk >> 6;
    }
    __syncthreads();

    // ---- aggregation: 4 waves x 16 nodes, verified gat inner loop ----
    int lane = t & 63;
    int w    = t >> 6;
    int g    = lane >> 4;     // edge slot 0..3
    int i4   = lane & 15;     // feature quad 0..15
    int iq   = i4 << 2;

    for (int nn_ = 0; nn_ < 16; ++nn_) {
        int n    = w * 16 + nn_;          // local node 0..63
        int node = node0 + n;
        if (node >= NN) break;
        int beg = loc[n];
        int end = beg + dcnt[n];

        float4 zd = *(const float4*)(z + (node << 6) + iq);
        float  m = -1e30f, ssum = 0.f;
        float4 h = {0.f, 0.f, 0.f, 0.f};

        for (int j = beg; j < end; j += 16) {
            int   off_[4];
            bool  val[4];
            float4 v[4];
            float p[4], e[4], ex[4];
            #pragma unroll
            for (int k = 0; k < 4; ++k) {
                int jj = j + k * 4 + g;
                val[k] = jj < end;
                off_[k] = (csr_l[val[k] ? jj : beg] << 6) + iq;
            }
            #pragma unroll
            for (int k = 0; k < 4; ++k)
                v[k] = *(const float4*)(z + off_[k]);
            #pragma unroll
            for (int k = 0; k < 4; ++k)
                p[k] = v[k].x * zd.x + v[k].y * zd.y + v[k].z * zd.z + v[k].w * zd.w;
            #pragma unroll
            for (int o = 1; o < 16; o <<= 1) {
                #pragma unroll
                for (int k = 0; k < 4; ++k) p[k] += __shfl_xor(p[k], o, 64);
            }
            #pragma unroll
            for (int k = 0; k < 4; ++k) {
                float ek = (p[k] > 0.f) ? p[k] : SLOPE * p[k];
                e[k] = val[k] ? ek : -1e30f;
            }
            float nm = fmaxf(m, fmaxf(fmaxf(e[0], e[1]), fmaxf(e[2], e[3])));
            float sc = __expf(m - nm);
            #pragma unroll
            for (int k = 0; k < 4; ++k) ex[k] = val[k] ? __expf(e[k] - nm) : 0.f;
            ssum = ssum * sc + ex[0] + ex[1] + ex[2] + ex[3];
            h.x = h.x * sc + ex[0] * v[0].x + ex[1] * v[1].x + ex[2] * v[2].x + ex[3] * v[3].x;
            h.y = h.y * sc + ex[0] * v[0].y + ex[1] * v[1].y + ex[2] * v[2].y + ex[3] * v[3].y;
            h.z = h.z * sc + ex[0] * v[0].z + ex[1] * v[1].z + ex[2] * v[2].z + ex[3] * v[3].z;
            h.w = h.w * sc + ex[0] * v[0].w + ex[1] * v[1].w + ex[2] * v[2].w + ex[3] * v[3].w;
            m = nm;
        }

        float M = fmaxf(m, __shfl_xor(m, 16, 64));
        M = fmaxf(M, __shfl_xor(M, 32, 64));
        float sc = __expf(m - M);
        float ss = ssum * sc;
        ss += __shfl_xor(ss, 16, 64);
        ss += __shfl_xor(ss, 32, 64);
        h.x *= sc; h.y *= sc; h.z *= sc; h.w *= sc;
        h.x += __shfl_xor(h.x, 16, 64); h.x += __shfl_xor(h.x, 32, 64);
        h.y += __shfl_xor(h.y, 16, 64); h.y += __shfl_xor(h.y, 32, 64);
        h.z += __shfl_xor(h.z, 16, 64); h.z += __shfl_xor(h.z, 32, 64);
        h.w += __shfl_xor(h.w, 16, 64); h.w += __shfl_xor(h.w, 32, 64);

        if (g == 0) {
            float rs = 1.0f / ss;
            bool has = end > beg;
            float4 o;
            o.x = has ? h.x * rs : 0.f;
            o.y = has ? h.y * rs : 0.f;
            o.z = has ? h.z * rs : 0.f;
            o.w = has ? h.w * rs : 0.f;
            o.x = (o.x > 0.f) ? o.x : (__expf(o.x) - 1.f);
            o.y = (o.y > 0.f) ? o.y : (__expf(o.y) - 1.f);
            o.z = (o.z > 0.f) ? o.z : (__expf(o.z) - 1.f);
            o.w = (o.w > 0.f) ? o.w : (__expf(o.w) - 1.f);
            *(float4*)(out + (node << 6) + iq) = o;
        }
    }
}

extern "C" void kernel_launch(void* const* d_in, const int* in_sizes, int n_in,
                              void* d_out, int out_size, void* d_ws, size_t ws_size,
                              hipStream_t stream) {
    const float* m_sim = (const float*)d_in[0];
    const float* d_sim = (const float*)d_in[1];
    const float* Wm    = (const float*)d_in[2];
    const float* Wd    = (const float*)d_in[3];
    const int*   src   = (const int*)d_in[4];
    const int*   dst   = (const int*)d_in[5];
    int E = in_sizes[4];
    float* out = (float*)d_out;

    char* ws = (char*)d_ws;
    float* z      = (float*)ws; ws += (size_t)NN * F * 4;
    int*   bcur   = (int*)ws;   ws += NPAD * 4;
    int*   pkb_g  = (int*)ws;   ws += (size_t)NB64 * QBCAP * 4;

    hipMemsetAsync(bcur, 0, NPAD * 4, stream);

    int nchunks = (E + CH - 1) / CH;   // 391
    fused1<<<nchunks + NPROJ, 512, 0, stream>>>(m_sim, d_sim, Wm, Wd, z,
                                                src, dst, pkb_g, bcur, nchunks, E);
    gat2<<<NB64, 256, 0, stream>>>(z, pkb_g, bcur, out);
}

// Round 23
// 125.024 us; speedup vs baseline: 1.1570x; 1.1570x over previous
//
#include <hip/hip_runtime.h>
#include <math.h>

#define NM 50000
#define ND 50000
#define NN 100000   // total nodes
#define DK 256      // feature dim of both sims
#define F  64       // attn feature size
#define SLOPE 0.2f

#define NBZ   391   // ceil(50000/128) proj blocks per half (128 rows/block)
#define NPROJ (NBZ * 2)

// edge binning: 256-node buckets
#define NBUCK 391   // ceil(100000/256)
#define BCAP  8192  // per-bucket capacity (avg fill 4092, sigma~64; 8192=+64sigma)
#define CH    4096  // edges per bin block
#define HCAP  3072  // per-half-bucket LDS csr capacity (mean 2046, +22sigma)

typedef short bf16x8 __attribute__((ext_vector_type(8)));
typedef float f32x4  __attribute__((ext_vector_type(4)));

// fp32 -> (hi, lo) bf16 split, rne both halves
__device__ __forceinline__ void cvt8(const float4& a0, const float4& a1,
                                     bf16x8& hi, bf16x8& lo) {
    float v[8] = {a0.x, a0.y, a0.z, a0.w, a1.x, a1.y, a1.z, a1.w};
    #pragma unroll
    for (int e = 0; e < 8; ++e) {
        unsigned u  = __float_as_uint(v[e]);
        unsigned r  = u + 0x7FFF + ((u >> 16) & 1);
        unsigned short hb = (unsigned short)(r >> 16);
        float hf = __uint_as_float(((unsigned)hb) << 16);
        float lf = v[e] - hf;
        unsigned ul = __float_as_uint(lf);
        unsigned rl = ul + 0x7FFF + ((ul >> 16) & 1);
        hi[e] = (short)hb;
        lo[e] = (short)(rl >> 16);
    }
}

// ================= fused kernel 1: bin (blocks 0..nchunks-1) ∥ proj (rest) =================
// Exact R20 form (empirical best): 256-node buckets, pk = (src<<8)|(dst&255).
__global__ __launch_bounds__(512, 1) void fused1(const float* __restrict__ m_sim,
                                                 const float* __restrict__ d_sim,
                                                 const float* __restrict__ Wm,
                                                 const float* __restrict__ Wd,
                                                 float* __restrict__ z,
                                                 const int* __restrict__ src,
                                                 const int* __restrict__ dst,
                                                 int* __restrict__ pkb_g,
                                                 int* __restrict__ bcur,
                                                 int nchunks, int E) {
    __shared__ __align__(16) char smem[65536];   // 64 KB union
    int t = threadIdx.x;

    if ((int)blockIdx.x < nchunks) {
        // ---------------- bin path (512 threads, ~40 KB) ----------------
        int* cnt   = (int*)smem;          // 512
        int* scx   = cnt + 512;           // 512
        int* lcur  = scx + 512;           // 512
        int* gbase = lcur + 512;          // 512
        int* pkb_l = gbase + 512;         // 4096
        int* bkt_l = pkb_l + CH;          // 4096

        int base = blockIdx.x * CH;
        int chunkN = E - base; if (chunkN > CH) chunkN = CH;

        cnt[t] = 0;
        __syncthreads();

        int ss[8], ds[8];
        #pragma unroll
        for (int e = 0; e < 8; ++e) {
            int k = base + e * 512 + t;
            if (e * 512 + t < chunkN) {
                ds[e] = dst[k];
                ss[e] = src[k];
                atomicAdd(&cnt[ds[e] >> 8], 1);
            }
        }
        __syncthreads();

        int x = cnt[t];
        scx[t] = x;
        __syncthreads();
        for (int off = 1; off < 512; off <<= 1) {
            int v = (t >= off) ? scx[t - off] : 0;
            __syncthreads();
            scx[t] += v;
            __syncthreads();
        }
        int lexcl = scx[t] - x;
        scx[t] = lexcl;
        lcur[t] = lexcl;
        gbase[t] = atomicAdd(&bcur[t], x);
        __syncthreads();

        #pragma unroll
        for (int e = 0; e < 8; ++e) {
            if (e * 512 + t < chunkN) {
                int b = ds[e] >> 8;
                int p = atomicAdd(&lcur[b], 1);
                pkb_l[p] = (ss[e] << 8) | (ds[e] & 255);
                bkt_l[p] = b;
            }
        }
        __syncthreads();

        for (int idx = t; idx < chunkN; idx += 512) {
            int b = bkt_l[idx];
            int g = b * BCAP + gbase[b] + (idx - scx[b]);
            pkb_g[g] = pkb_l[idx];
        }
        return;
    }

    // ---------------- proj path (512 threads, 64 KB) ----------------
    short* Whi = (short*)smem;            // 64 x 256 bf16 = 32 KB, ps = ls^(row&7)
    short* Wlo = (short*)(smem + 32768);  // 32 KB

    int bid  = blockIdx.x - nchunks;
    bool ism = bid < NBZ;
    const float* sim = ism ? m_sim : d_sim;
    const float* W   = ism ? Wm : Wd;
    int row0   = (ism ? bid : bid - NBZ) * 128;
    int nrows  = ism ? NM : ND;
    int zbase  = ism ? 0 : NM;

    int l = t & 63;           // lane
    int w = t >> 6;           // wave 0..7
    int frow = l & 15;        // A row within wave stripe / B col within tile
    int kg   = l >> 4;        // k-group 0..3

    int grow = row0 + w * 16 + frow; if (grow > nrows - 1) grow = nrows - 1;
    const float4* ap = (const float4*)(sim + (size_t)grow * DK) + kg * 2;

    // prefetch steps 0 and 1 (land during W conversion)
    float4 pa0 = ap[0], pa1 = ap[1];
    float4 pb0 = ap[8], pb1 = ap[9];

    // ---- W -> LDS bf16 hi+lo, once per block (write-side XOR ps = ls^(r&7)) ----
    {
        int r = t >> 3;                   // row 0..63
        int q = t & 7;                    // slot quarter 0..7
        const float4* wr = (const float4*)(W + (size_t)r * DK);
        #pragma unroll
        for (int i = 0; i < 4; ++i) {
            int ls = q * 4 + i;           // logical slot 0..31
            float4 b0 = wr[ls * 2], b1 = wr[ls * 2 + 1];
            bf16x8 hi, lo;
            cvt8(b0, b1, hi, lo);
            int ps = ls ^ (r & 7);
            *(bf16x8*)&Whi[r * 256 + ps * 8] = hi;
            *(bf16x8*)&Wlo[r * 256 + ps * 8] = lo;
        }
    }
    __syncthreads();   // W tiles ready; no further barriers needed

    f32x4 acc[4];
    #pragma unroll
    for (int j = 0; j < 4; ++j) acc[j] = (f32x4){0.f, 0.f, 0.f, 0.f};

    #pragma unroll 1
    for (int step = 0; step < 8; ++step) {
        bf16x8 ahi, alo;
        cvt8(pa0, pa1, ahi, alo);
        pa0 = pb0; pa1 = pb1;
        if (step + 2 < 8) {
            pb0 = ap[(step + 2) * 8];
            pb1 = ap[(step + 2) * 8 + 1];
        }

        int ls = step * 4 + kg;
        #pragma unroll
        for (int j = 0; j < 4; ++j) {
            int wrow = j * 16 + frow;
            int ps = ls ^ (wrow & 7);
            bf16x8 bhi = *(const bf16x8*)&Whi[wrow * 256 + ps * 8];
            bf16x8 blo = *(const bf16x8*)&Wlo[wrow * 256 + ps * 8];
            acc[j] = __builtin_amdgcn_mfma_f32_16x16x32_bf16(ahi, bhi, acc[j], 0, 0, 0);
            acc[j] = __builtin_amdgcn_mfma_f32_16x16x32_bf16(ahi, blo, acc[j], 0, 0, 0);
            acc[j] = __builtin_amdgcn_mfma_f32_16x16x32_bf16(alo, bhi, acc[j], 0, 0, 0);
        }
    }

    // D layout (verified m89): col = lane&15, row = (lane>>4)*4 + reg
    #pragma unroll
    for (int j = 0; j < 4; ++j) {
        #pragma unroll
        for (int reg = 0; reg < 4; ++reg) {
            int r = row0 + w * 16 + kg * 4 + reg;
            if (r < nrows)
                z[((zbase + r) << 6) + j * 16 + frow] = acc[j][reg];
        }
    }
}

// ================= gat2h: half-bucket (128 nodes), 512 thr, single-pass reg-held =================
// R22 BUG: 8 edges/thread covered only 4096 slots but nbe averages 4092 (sigma 64)
// -> ~half the buckets dropped tail edges (absmax 4.4). Fix: 16 edges/thread =
// 8192 = BCAP, coverage guaranteed by the bin capacity bound.
__global__ __launch_bounds__(512) void gat2h(const float* __restrict__ z,
                                             const int* __restrict__ pkb_g,
                                             const int* __restrict__ bcur,
                                             float* __restrict__ out) {
    __shared__ int dcnt[128], loc[128], lcur[128];
    __shared__ int csr_l[HCAP];

    int t  = threadIdx.x;
    int b  = blockIdx.x >> 1;     // bucket
    int hh = blockIdx.x & 1;      // half
    int node0 = (b << 8) + (hh << 7);
    int nbe = bcur[b];
    const int* pp = pkb_g + (size_t)b * BCAP;

    if (t < 128) dcnt[t] = 0;
    __syncthreads();

    int ed[16]; bool kv[16];
    #pragma unroll
    for (int e = 0; e < 16; ++e) {
        int i = e * 512 + t;      // covers 0..8191 = BCAP
        bool v = i < nbe;
        int pk = v ? pp[i] : 0;
        kv[e] = v && (((pk >> 7) & 1) == hh);
        ed[e] = pk;
    }
    #pragma unroll
    for (int e = 0; e < 16; ++e)
        if (kv[e]) atomicAdd(&dcnt[ed[e] & 127], 1);
    __syncthreads();

    if (t < 128) loc[t] = dcnt[t];
    __syncthreads();
    for (int off = 1; off < 128; off <<= 1) {
        int v = (t < 128 && t >= off) ? loc[t - off] : 0;
        __syncthreads();
        if (t < 128) loc[t] += v;
        __syncthreads();
    }
    if (t < 128) { int e0 = loc[t] - dcnt[t]; loc[t] = e0; lcur[t] = e0; }
    __syncthreads();

    #pragma unroll
    for (int e = 0; e < 16; ++e) {
        if (kv[e]) {
            int pos = atomicAdd(&lcur[ed[e] & 127], 1);
            csr_l[pos] = ed[e] >> 8;
        }
    }
    __syncthreads();

    // ---- aggregation: 8 waves x 16 nodes, verified gat inner loop ----
    int lane = t & 63;
    int w    = t >> 6;        // wave 0..7
    int g    = lane >> 4;     // edge slot 0..3
    int i4   = lane & 15;     // feature quad 0..15
    int iq   = i4 << 2;

    for (int nn_ = 0; nn_ < 16; ++nn_) {
        int n    = w * 16 + nn_;          // local node 0..127
        int node = node0 + n;
        if (node >= NN) break;
        int beg = loc[n];
        int end = beg + dcnt[n];

        float4 zd = *(const float4*)(z + (node << 6) + iq);
        float  m = -1e30f, ssum = 0.f;
        float4 h = {0.f, 0.f, 0.f, 0.f};

        for (int j = beg; j < end; j += 16) {
            int   off_[4];
            bool  val[4];
            float4 v[4];
            float p[4], e[4], ex[4];
            #pragma unroll
            for (int k = 0; k < 4; ++k) {
                int jj = j + k * 4 + g;
                val[k] = jj < end;
                off_[k] = (csr_l[val[k] ? jj : beg] << 6) + iq;
            }
            #pragma unroll
            for (int k = 0; k < 4; ++k)
                v[k] = *(const float4*)(z + off_[k]);
            #pragma unroll
            for (int k = 0; k < 4; ++k)
                p[k] = v[k].x * zd.x + v[k].y * zd.y + v[k].z * zd.z + v[k].w * zd.w;
            #pragma unroll
            for (int o = 1; o < 16; o <<= 1) {
                #pragma unroll
                for (int k = 0; k < 4; ++k) p[k] += __shfl_xor(p[k], o, 64);
            }
            #pragma unroll
            for (int k = 0; k < 4; ++k) {
                float ek = (p[k] > 0.f) ? p[k] : SLOPE * p[k];
                e[k] = val[k] ? ek : -1e30f;
            }
            float nm = fmaxf(m, fmaxf(fmaxf(e[0], e[1]), fmaxf(e[2], e[3])));
            float sc = __expf(m - nm);
            #pragma unroll
            for (int k = 0; k < 4; ++k) ex[k] = val[k] ? __expf(e[k] - nm) : 0.f;
            ssum = ssum * sc + ex[0] + ex[1] + ex[2] + ex[3];
            h.x = h.x * sc + ex[0] * v[0].x + ex[1] * v[1].x + ex[2] * v[2].x + ex[3] * v[3].x;
            h.y = h.y * sc + ex[0] * v[0].y + ex[1] * v[1].y + ex[2] * v[2].y + ex[3] * v[3].y;
            h.z = h.z * sc + ex[0] * v[0].z + ex[1] * v[1].z + ex[2] * v[2].z + ex[3] * v[3].z;
            h.w = h.w * sc + ex[0] * v[0].w + ex[1] * v[1].w + ex[2] * v[2].w + ex[3] * v[3].w;
            m = nm;
        }

        float M = fmaxf(m, __shfl_xor(m, 16, 64));
        M = fmaxf(M, __shfl_xor(M, 32, 64));
        float sc = __expf(m - M);
        float ss = ssum * sc;
        ss += __shfl_xor(ss, 16, 64);
        ss += __shfl_xor(ss, 32, 64);
        h.x *= sc; h.y *= sc; h.z *= sc; h.w *= sc;
        h.x += __shfl_xor(h.x, 16, 64); h.x += __shfl_xor(h.x, 32, 64);
        h.y += __shfl_xor(h.y, 16, 64); h.y += __shfl_xor(h.y, 32, 64);
        h.z += __shfl_xor(h.z, 16, 64); h.z += __shfl_xor(h.z, 32, 64);
        h.w += __shfl_xor(h.w, 16, 64); h.w += __shfl_xor(h.w, 32, 64);

        if (g == 0) {
            float rs = 1.0f / ss;
            bool has = end > beg;
            float4 o;
            o.x = has ? h.x * rs : 0.f;
            o.y = has ? h.y * rs : 0.f;
            o.z = has ? h.z * rs : 0.f;
            o.w = has ? h.w * rs : 0.f;
            o.x = (o.x > 0.f) ? o.x : (__expf(o.x) - 1.f);
            o.y = (o.y > 0.f) ? o.y : (__expf(o.y) - 1.f);
            o.z = (o.z > 0.f) ? o.z : (__expf(o.z) - 1.f);
            o.w = (o.w > 0.f) ? o.w : (__expf(o.w) - 1.f);
            *(float4*)(out + (node << 6) + iq) = o;
        }
    }
}

extern "C" void kernel_launch(void* const* d_in, const int* in_sizes, int n_in,
                              void* d_out, int out_size, void* d_ws, size_t ws_size,
                              hipStream_t stream) {
    const float* m_sim = (const float*)d_in[0];
    const float* d_sim = (const float*)d_in[1];
    const float* Wm    = (const float*)d_in[2];
    const float* Wd    = (const float*)d_in[3];
    const int*   src   = (const int*)d_in[4];
    const int*   dst   = (const int*)d_in[5];
    int E = in_sizes[4];
    float* out = (float*)d_out;

    char* ws = (char*)d_ws;
    float* z      = (float*)ws; ws += (size_t)NN * F * 4;
    int*   bcur   = (int*)ws;   ws += 512 * 4;
    int*   pkb_g  = (int*)ws;   ws += (size_t)NBUCK * BCAP * 4;

    hipMemsetAsync(bcur, 0, 512 * 4, stream);

    int nchunks = (E + CH - 1) / CH;   // 391
    fused1<<<nchunks + NPROJ, 512, 0, stream>>>(m_sim, d_sim, Wm, Wd, z,
                                                src, dst, pkb_g, bcur, nchunks, E);
    gat2h<<<NBUCK * 2, 512, 0, stream>>>(z, pkb_g, bcur, out);
}